// Round 1
// baseline (883.005 us; speedup 1.0000x reference)
//
#include <hip/hip_runtime.h>
#include <hip/hip_bf16.h>
#include <math.h>

#define B_   16384
#define IN_  1024
#define HID_ 1024
#define D_   64

__device__ __forceinline__ float sigmoidf_(float x) { return 1.0f / (1.0f + expf(-x)); }

// ---------------------------------------------------------------------------
// K1: q/k/v projections.  grid (B/128, 3), block 256.
// Block computes 128 rows x 64 cols of out = x @ W^T + b, W in {Wq,Wk,Wv}.
// ---------------------------------------------------------------------------
__global__ __launch_bounds__(256) void proj_qkv(
    const float* __restrict__ x,
    const float* __restrict__ Wq, const float* __restrict__ bq,
    const float* __restrict__ Wk, const float* __restrict__ bk,
    const float* __restrict__ Wv, const float* __restrict__ bv,
    float* __restrict__ qo, float* __restrict__ ko, float* __restrict__ vo)
{
    const int which = blockIdx.y;
    const float* __restrict__ W  = (which == 0) ? Wq : (which == 1) ? Wk : Wv;
    const float* __restrict__ bs = (which == 0) ? bq : (which == 1) ? bk : bv;
    float* __restrict__ out      = (which == 0) ? qo : (which == 1) ? ko : vo;

    __shared__ float As[16][132];   // x^T tile: As[k][r], rows 0..127
    __shared__ float Bs[16][68];    // W^T tile: Bs[k][c], cols 0..63

    const int t  = threadIdx.x;
    const int tm = t >> 4;          // 0..15
    const int tn = t & 15;          // 0..15
    const int row0 = blockIdx.x * 128;

    float acc[2][4][4] = {};

    for (int k0 = 0; k0 < IN_; k0 += 16) {
        __syncthreads();
        {   // stage x tile 128x16 (2 float4 per thread)
            int f = t;
            #pragma unroll
            for (int rep = 0; rep < 2; ++rep, f += 256) {
                const int r  = f >> 2;
                const int kq = (f & 3) * 4;
                const float4 g = *reinterpret_cast<const float4*>(
                    &x[(size_t)(row0 + r) * IN_ + k0 + kq]);
                As[kq + 0][r] = g.x; As[kq + 1][r] = g.y;
                As[kq + 2][r] = g.z; As[kq + 3][r] = g.w;
            }
        }
        {   // stage W tile 64x16 (1 float4 per thread)
            const int c  = t >> 2;
            const int kq = (t & 3) * 4;
            const float4 g = *reinterpret_cast<const float4*>(
                &W[(size_t)c * IN_ + k0 + kq]);
            Bs[kq + 0][c] = g.x; Bs[kq + 1][c] = g.y;
            Bs[kq + 2][c] = g.z; Bs[kq + 3][c] = g.w;
        }
        __syncthreads();
        #pragma unroll
        for (int kk = 0; kk < 16; ++kk) {
            const float4 a0 = *reinterpret_cast<const float4*>(&As[kk][tm * 4]);
            const float4 a1 = *reinterpret_cast<const float4*>(&As[kk][64 + tm * 4]);
            const float4 b0 = *reinterpret_cast<const float4*>(&Bs[kk][tn * 4]);
            const float ar[8] = {a0.x, a0.y, a0.z, a0.w, a1.x, a1.y, a1.z, a1.w};
            const float br[4] = {b0.x, b0.y, b0.z, b0.w};
            #pragma unroll
            for (int qa = 0; qa < 2; ++qa)
                #pragma unroll
                for (int i = 0; i < 4; ++i)
                    #pragma unroll
                    for (int j = 0; j < 4; ++j)
                        acc[qa][i][j] = fmaf(ar[qa * 4 + i], br[j], acc[qa][i][j]);
        }
    }

    const float4 b4 = *reinterpret_cast<const float4*>(&bs[tn * 4]);
    #pragma unroll
    for (int qa = 0; qa < 2; ++qa)
        #pragma unroll
        for (int i = 0; i < 4; ++i) {
            const int r = row0 + qa * 64 + tm * 4 + i;
            float4 o;
            o.x = acc[qa][i][0] + b4.x;
            o.y = acc[qa][i][1] + b4.y;
            o.z = acc[qa][i][2] + b4.z;
            o.w = acc[qa][i][3] + b4.w;
            *reinterpret_cast<float4*>(&out[(size_t)r * D_ + tn * 4]) = o;
        }
}

// ---------------------------------------------------------------------------
// K2: i/f gates.  grid (B/16), block 256 (4 waves x 4 rows each).
// ---------------------------------------------------------------------------
__global__ __launch_bounds__(256) void gates_if(
    const float* __restrict__ x,
    const float* __restrict__ Wi, const float* __restrict__ bi,
    const float* __restrict__ Wf, const float* __restrict__ bf,
    float* __restrict__ ig, float* __restrict__ fg)
{
    const int wave = threadIdx.x >> 6;
    const int lane = threadIdx.x & 63;
    const int row0 = blockIdx.x * 16 + wave * 4;

    for (int rr = 0; rr < 4; ++rr) {
        const int r = row0 + rr;
        const float* __restrict__ xr = x + (size_t)r * IN_;
        float si = 0.f, sf = 0.f;
        for (int k = lane; k < IN_; k += 64) {
            const float xv = xr[k];
            si = fmaf(xv, Wi[k], si);
            sf = fmaf(xv, Wf[k], sf);
        }
        #pragma unroll
        for (int off = 32; off > 0; off >>= 1) {
            si += __shfl_down(si, off);
            sf += __shfl_down(sf, off);
        }
        if (lane == 0) {
            ig[r] = expf(si + bi[0]);
            fg[r] = sigmoidf_(sf + bf[0]);
        }
    }
}

// ---------------------------------------------------------------------------
// K3: cell update: C_new = f*C + i*v(x)k ; n_new = f*n + i ;
//     h_tilde = (C_new @ q) / (n_new + 1e-8).   grid (B), block 256.
// ---------------------------------------------------------------------------
__global__ __launch_bounds__(256) void cell_update(
    const float* __restrict__ C,
    const float* __restrict__ q, const float* __restrict__ k,
    const float* __restrict__ v,
    const float* __restrict__ ig, const float* __restrict__ fg,
    const float* __restrict__ n,
    float* __restrict__ C_new, float* __restrict__ n_new,
    float* __restrict__ ht)
{
    const int b    = blockIdx.x;
    const int wave = threadIdx.x >> 6;
    const int lane = threadIdx.x & 63;

    const float iv = ig[b];
    const float fv = fg[b];
    const float nn = fv * n[b] + iv;
    if (threadIdx.x == 0) n_new[b] = nn;
    const float inv = 1.0f / (nn + 1e-8f);

    const float qv = q[(size_t)b * D_ + lane];
    const float kv = k[(size_t)b * D_ + lane];
    const float* __restrict__ Cb  = C     + (size_t)b * D_ * D_;
    float* __restrict__       Cnb = C_new + (size_t)b * D_ * D_;

    for (int i = wave; i < D_; i += 4) {
        const float vi = v[(size_t)b * D_ + i];
        const float cn = fmaf(fv, Cb[i * D_ + lane], iv * vi * kv);
        Cnb[i * D_ + lane] = cn;
        float p = cn * qv;
        #pragma unroll
        for (int off = 32; off > 0; off >>= 1) p += __shfl_down(p, off);
        if (lane == 0) ht[(size_t)b * D_ + i] = p * inv;
    }
}

// ---------------------------------------------------------------------------
// K4: fused output: h_new = sigmoid(x@Wo^T+bo) * tanh(ht@Wp^T+bp)
//     grid (B/128, HID/128), block 256, 8x8 micro-tile in 4 quadrants.
// ---------------------------------------------------------------------------
__global__ __launch_bounds__(256) void out_fused(
    const float* __restrict__ x,  const float* __restrict__ Wo, const float* __restrict__ bo,
    const float* __restrict__ ht, const float* __restrict__ Wp, const float* __restrict__ bp,
    float* __restrict__ h_new)
{
    __shared__ float As[16][132];
    __shared__ float Bs[16][132];

    const int t  = threadIdx.x;
    const int tm = t >> 4;
    const int tn = t & 15;
    const int row0 = blockIdx.x * 128;
    const int col0 = blockIdx.y * 128;

    float acc_o[2][2][4][4] = {};
    float acc_p[2][2][4][4] = {};

    // ---- phase 1: acc_o += x(128xK) @ Wo(128xK)^T, K = 1024 ----
    for (int k0 = 0; k0 < IN_; k0 += 16) {
        __syncthreads();
        int f = t;
        #pragma unroll
        for (int rep = 0; rep < 2; ++rep, f += 256) {
            const int r  = f >> 2;
            const int kq = (f & 3) * 4;
            const float4 ga = *reinterpret_cast<const float4*>(
                &x[(size_t)(row0 + r) * IN_ + k0 + kq]);
            As[kq + 0][r] = ga.x; As[kq + 1][r] = ga.y;
            As[kq + 2][r] = ga.z; As[kq + 3][r] = ga.w;
            const float4 gb = *reinterpret_cast<const float4*>(
                &Wo[(size_t)(col0 + r) * IN_ + k0 + kq]);
            Bs[kq + 0][r] = gb.x; Bs[kq + 1][r] = gb.y;
            Bs[kq + 2][r] = gb.z; Bs[kq + 3][r] = gb.w;
        }
        __syncthreads();
        #pragma unroll
        for (int kk = 0; kk < 16; ++kk) {
            const float4 a0 = *reinterpret_cast<const float4*>(&As[kk][tm * 4]);
            const float4 a1 = *reinterpret_cast<const float4*>(&As[kk][64 + tm * 4]);
            const float4 b0 = *reinterpret_cast<const float4*>(&Bs[kk][tn * 4]);
            const float4 b1 = *reinterpret_cast<const float4*>(&Bs[kk][64 + tn * 4]);
            const float ar[8] = {a0.x, a0.y, a0.z, a0.w, a1.x, a1.y, a1.z, a1.w};
            const float br[8] = {b0.x, b0.y, b0.z, b0.w, b1.x, b1.y, b1.z, b1.w};
            #pragma unroll
            for (int qa = 0; qa < 2; ++qa)
                #pragma unroll
                for (int qb = 0; qb < 2; ++qb)
                    #pragma unroll
                    for (int i = 0; i < 4; ++i)
                        #pragma unroll
                        for (int j = 0; j < 4; ++j)
                            acc_o[qa][qb][i][j] =
                                fmaf(ar[qa * 4 + i], br[qb * 4 + j], acc_o[qa][qb][i][j]);
        }
    }

    // ---- phase 2: acc_p += ht(128xK) @ Wp(128xK)^T, K = 64 ----
    for (int k0 = 0; k0 < D_; k0 += 16) {
        __syncthreads();
        int f = t;
        #pragma unroll
        for (int rep = 0; rep < 2; ++rep, f += 256) {
            const int r  = f >> 2;
            const int kq = (f & 3) * 4;
            const float4 ga = *reinterpret_cast<const float4*>(
                &ht[(size_t)(row0 + r) * D_ + k0 + kq]);
            As[kq + 0][r] = ga.x; As[kq + 1][r] = ga.y;
            As[kq + 2][r] = ga.z; As[kq + 3][r] = ga.w;
            const float4 gb = *reinterpret_cast<const float4*>(
                &Wp[(size_t)(col0 + r) * D_ + k0 + kq]);
            Bs[kq + 0][r] = gb.x; Bs[kq + 1][r] = gb.y;
            Bs[kq + 2][r] = gb.z; Bs[kq + 3][r] = gb.w;
        }
        __syncthreads();
        #pragma unroll
        for (int kk = 0; kk < 16; ++kk) {
            const float4 a0 = *reinterpret_cast<const float4*>(&As[kk][tm * 4]);
            const float4 a1 = *reinterpret_cast<const float4*>(&As[kk][64 + tm * 4]);
            const float4 b0 = *reinterpret_cast<const float4*>(&Bs[kk][tn * 4]);
            const float4 b1 = *reinterpret_cast<const float4*>(&Bs[kk][64 + tn * 4]);
            const float ar[8] = {a0.x, a0.y, a0.z, a0.w, a1.x, a1.y, a1.z, a1.w};
            const float br[8] = {b0.x, b0.y, b0.z, b0.w, b1.x, b1.y, b1.z, b1.w};
            #pragma unroll
            for (int qa = 0; qa < 2; ++qa)
                #pragma unroll
                for (int qb = 0; qb < 2; ++qb)
                    #pragma unroll
                    for (int i = 0; i < 4; ++i)
                        #pragma unroll
                        for (int j = 0; j < 4; ++j)
                            acc_p[qa][qb][i][j] =
                                fmaf(ar[qa * 4 + i], br[qb * 4 + j], acc_p[qa][qb][i][j]);
        }
    }

    // ---- epilogue ----
    #pragma unroll
    for (int qb = 0; qb < 2; ++qb) {
        const int c = col0 + qb * 64 + tn * 4;
        const float4 bo4 = *reinterpret_cast<const float4*>(&bo[c]);
        const float4 bp4 = *reinterpret_cast<const float4*>(&bp[c]);
        #pragma unroll
        for (int qa = 0; qa < 2; ++qa)
            #pragma unroll
            for (int i = 0; i < 4; ++i) {
                const int r = row0 + qa * 64 + tm * 4 + i;
                float4 hv;
                hv.x = sigmoidf_(acc_o[qa][qb][i][0] + bo4.x) * tanhf(acc_p[qa][qb][i][0] + bp4.x);
                hv.y = sigmoidf_(acc_o[qa][qb][i][1] + bo4.y) * tanhf(acc_p[qa][qb][i][1] + bp4.y);
                hv.z = sigmoidf_(acc_o[qa][qb][i][2] + bo4.z) * tanhf(acc_p[qa][qb][i][2] + bp4.z);
                hv.w = sigmoidf_(acc_o[qa][qb][i][3] + bo4.w) * tanhf(acc_p[qa][qb][i][3] + bp4.w);
                *reinterpret_cast<float4*>(&h_new[(size_t)r * HID_ + c]) = hv;
            }
    }
}

// ---------------------------------------------------------------------------
extern "C" void kernel_launch(void* const* d_in, const int* in_sizes, int n_in,
                              void* d_out, int out_size, void* d_ws, size_t ws_size,
                              hipStream_t stream)
{
    (void)in_sizes; (void)n_in; (void)out_size; (void)ws_size;

    const float* x  = (const float*)d_in[0];
    // d_in[1] = h (unused by the reference)
    const float* C  = (const float*)d_in[2];
    const float* n  = (const float*)d_in[3];
    const float* Wq = (const float*)d_in[4];
    const float* bq = (const float*)d_in[5];
    const float* Wk = (const float*)d_in[6];
    const float* bk = (const float*)d_in[7];
    const float* Wv = (const float*)d_in[8];
    const float* bv = (const float*)d_in[9];
    const float* Wi = (const float*)d_in[10];
    const float* bi = (const float*)d_in[11];
    const float* Wf = (const float*)d_in[12];
    const float* bf = (const float*)d_in[13];
    const float* Wo = (const float*)d_in[14];
    const float* bo = (const float*)d_in[15];
    const float* Wp = (const float*)d_in[16];
    const float* bp = (const float*)d_in[17];

    float* h_new = (float*)d_out;
    float* C_new = h_new + (size_t)B_ * HID_;
    float* n_new = C_new + (size_t)B_ * D_ * D_;

    float* ws = (float*)d_ws;
    float* q  = ws;
    float* k  = ws + (size_t)B_ * D_;
    float* v  = ws + 2 * (size_t)B_ * D_;
    float* ig = ws + 3 * (size_t)B_ * D_;
    float* fg = ig + B_;
    float* ht = fg + B_;

    proj_qkv<<<dim3(B_ / 128, 3), 256, 0, stream>>>(x, Wq, bq, Wk, bk, Wv, bv, q, k, v);
    gates_if<<<dim3(B_ / 16), 256, 0, stream>>>(x, Wi, bi, Wf, bf, ig, fg);
    cell_update<<<dim3(B_), 256, 0, stream>>>(C, q, k, v, ig, fg, n, C_new, n_new, ht);
    out_fused<<<dim3(B_ / 128, HID_ / 128), 256, 0, stream>>>(x, Wo, bo, ht, Wp, bp, h_new);
}

// Round 2
// 309.829 us; speedup vs baseline: 2.8500x; 2.8500x over previous
//
#include <hip/hip_runtime.h>
#include <hip/hip_bf16.h>
#include <math.h>

#define B_   16384
#define IN_  1024
#define HID_ 1024
#define D_   64

typedef float  f32x4  __attribute__((ext_vector_type(4)));
typedef short  short8 __attribute__((ext_vector_type(8)));
typedef __bf16 bf16x8 __attribute__((ext_vector_type(8)));

__device__ __forceinline__ unsigned short f2bf(float f) {
    unsigned u = __builtin_bit_cast(unsigned, f);
    u += 0x7fffu + ((u >> 16) & 1u);          // RTNE
    return (unsigned short)(u >> 16);
}

__device__ __forceinline__ f32x4 mfma16x16x32(short8 a, short8 b, f32x4 c) {
    return __builtin_amdgcn_mfma_f32_16x16x32_bf16(
        __builtin_bit_cast(bf16x8, a), __builtin_bit_cast(bf16x8, b), c, 0, 0, 0);
}

__device__ __forceinline__ float sigmoidf_(float x) { return 1.0f / (1.0f + __expf(-x)); }
__device__ __forceinline__ float tanhf_(float x) {
    x = fminf(fmaxf(x, -15.f), 15.f);
    float e = __expf(2.f * x);
    return (e - 1.f) / (e + 1.f);
}

// ---------------------------------------------------------------------------
// K0: convert weights to bf16.  Wqkv_b = [Wq;Wk;Wv] (192x1024), Wo_b, Wp_b.
// grid 1280, block 256, 4 elems/thread.
// ---------------------------------------------------------------------------
__global__ __launch_bounds__(256) void cvt_w(
    const float* __restrict__ Wq, const float* __restrict__ Wk,
    const float* __restrict__ Wv, const float* __restrict__ Wo,
    const float* __restrict__ Wp,
    ushort* __restrict__ Wqkv_b, ushort* __restrict__ Wo_b, ushort* __restrict__ Wp_b)
{
    const size_t base = (size_t)blockIdx.x * 1024 + (size_t)threadIdx.x * 4;
    const float* src;  ushort* dst;
    if (base < 196608) {
        dst = Wqkv_b + base;
        src = (base < 65536) ? Wq + base
            : (base < 131072) ? Wk + (base - 65536)
                              : Wv + (base - 131072);
    } else if (base < 196608 + 1048576) {
        dst = Wo_b + (base - 196608);
        src = Wo   + (base - 196608);
    } else {
        dst = Wp_b + (base - 1245184);
        src = Wp   + (base - 1245184);
    }
    const float4 g = *reinterpret_cast<const float4*>(src);
    ushort4 o;
    o.x = f2bf(g.x); o.y = f2bf(g.y); o.z = f2bf(g.z); o.w = f2bf(g.w);
    *reinterpret_cast<ushort4*>(dst) = o;
}

// ---------------------------------------------------------------------------
// K1: q/k/v projection via MFMA.  Tile 64 rows x 192 cols, K=1024.
// grid 256, block 256 (4 waves; wave w -> cols w*48..w*48+47).
// ---------------------------------------------------------------------------
__global__ __launch_bounds__(256) void proj_qkv(
    const float* __restrict__ x, const ushort* __restrict__ Wqkv_b,
    const float* __restrict__ bq, const float* __restrict__ bk, const float* __restrict__ bv,
    float* __restrict__ qo, float* __restrict__ ko, float* __restrict__ vo)
{
    __shared__ __align__(16) ushort As[64][32];
    __shared__ __align__(16) ushort Bs[192][32];

    const int t = threadIdx.x;
    const int w = t >> 6, l = t & 63;
    const int l4 = l >> 4, l15 = l & 15;
    const int mrow = blockIdx.x * 64;

    const int srow = t >> 3;           // 0..31 (fp32 staging)
    const int skq  = (t & 7) * 4;
    const int rb   = t >> 2;           // 0..63 (bf16 staging)
    const int kb   = (t & 3) * 8;

    f32x4 acc[4][3] = {};

    for (int k0 = 0; k0 < IN_; k0 += 32) {
        __syncthreads();
        // A: x 64x32, fp32 -> bf16
        #pragma unroll
        for (int s = 0; s < 2; ++s) {
            const int r = srow + s * 32;
            const float4 g = *reinterpret_cast<const float4*>(
                &x[(size_t)(mrow + r) * IN_ + k0 + skq]);
            ushort p[4] = {f2bf(g.x), f2bf(g.y), f2bf(g.z), f2bf(g.w)};
            *reinterpret_cast<ushort4*>(&As[r][skq]) = *reinterpret_cast<ushort4*>(p);
        }
        // B: Wqkv_b 192x32, bf16 direct 16B copies
        #pragma unroll
        for (int s = 0; s < 3; ++s) {
            const int r = rb + s * 64;
            *reinterpret_cast<short8*>(&Bs[r][kb]) =
                *reinterpret_cast<const short8*>(&Wqkv_b[(size_t)r * IN_ + k0 + kb]);
        }
        __syncthreads();

        short8 af[4], bf_[3];
        #pragma unroll
        for (int m = 0; m < 4; ++m)
            af[m] = *reinterpret_cast<const short8*>(&As[m * 16 + l15][l4 * 8]);
        #pragma unroll
        for (int n = 0; n < 3; ++n)
            bf_[n] = *reinterpret_cast<const short8*>(&Bs[w * 48 + n * 16 + l15][l4 * 8]);
        #pragma unroll
        for (int m = 0; m < 4; ++m)
            #pragma unroll
            for (int n = 0; n < 3; ++n)
                acc[m][n] = mfma16x16x32(af[m], bf_[n], acc[m][n]);
    }

    // epilogue: c in [0,192) -> matrix c/64, col c%64
    #pragma unroll
    for (int n = 0; n < 3; ++n) {
        const int c   = w * 48 + n * 16 + l15;
        const int mtx = c >> 6, lc = c & 63;
        float* __restrict__ out = (mtx == 0) ? qo : (mtx == 1) ? ko : vo;
        const float* __restrict__ bb = (mtx == 0) ? bq : (mtx == 1) ? bk : bv;
        const float bias = bb[lc];
        #pragma unroll
        for (int m = 0; m < 4; ++m)
            #pragma unroll
            for (int r = 0; r < 4; ++r) {
                const int row = mrow + m * 16 + l4 * 4 + r;
                out[(size_t)row * D_ + lc] = acc[m][n][r] + bias;
            }
    }
}

// ---------------------------------------------------------------------------
// K2: i/f gates (unchanged from round 1).
// ---------------------------------------------------------------------------
__global__ __launch_bounds__(256) void gates_if(
    const float* __restrict__ x,
    const float* __restrict__ Wi, const float* __restrict__ bi,
    const float* __restrict__ Wf, const float* __restrict__ bf,
    float* __restrict__ ig, float* __restrict__ fg)
{
    const int wave = threadIdx.x >> 6;
    const int lane = threadIdx.x & 63;
    const int row0 = blockIdx.x * 16 + wave * 4;

    for (int rr = 0; rr < 4; ++rr) {
        const int r = row0 + rr;
        const float* __restrict__ xr = x + (size_t)r * IN_;
        float si = 0.f, sf = 0.f;
        for (int k = lane; k < IN_; k += 64) {
            const float xv = xr[k];
            si = fmaf(xv, Wi[k], si);
            sf = fmaf(xv, Wf[k], sf);
        }
        #pragma unroll
        for (int off = 32; off > 0; off >>= 1) {
            si += __shfl_down(si, off);
            sf += __shfl_down(sf, off);
        }
        if (lane == 0) {
            ig[r] = __expf(si + bi[0]);
            fg[r] = 1.0f / (1.0f + __expf(-(sf + bf[0])));
        }
    }
}

// ---------------------------------------------------------------------------
// K3: cell update (float4-vectorized).  grid B, block 256.
// thread t: row i = t>>2, col-quarter p = t&3 (16 cols).
// ---------------------------------------------------------------------------
__global__ __launch_bounds__(256) void cell_update(
    const float* __restrict__ C,
    const float* __restrict__ q, const float* __restrict__ k,
    const float* __restrict__ v,
    const float* __restrict__ ig, const float* __restrict__ fg,
    const float* __restrict__ n,
    float* __restrict__ C_new, float* __restrict__ n_new,
    ushort* __restrict__ ht)
{
    const int b = blockIdx.x;
    const int t = threadIdx.x;
    const int i = t >> 2;
    const int p = t & 3;

    const float iv = ig[b];
    const float fv = fg[b];
    const float nn = fv * n[b] + iv;
    if (t == 0) n_new[b] = nn;
    const float inv = 1.0f / (nn + 1e-8f);

    const float* __restrict__ qb  = q + (size_t)b * D_ + p * 16;
    const float* __restrict__ kb  = k + (size_t)b * D_ + p * 16;
    const float  vi = v[(size_t)b * D_ + i] * iv;
    const float* __restrict__ Cb  = C     + (size_t)b * D_ * D_ + i * D_ + p * 16;
    float* __restrict__       Cnb = C_new + (size_t)b * D_ * D_ + i * D_ + p * 16;

    float dot = 0.f;
    #pragma unroll
    for (int j = 0; j < 4; ++j) {
        const float4 c4 = *reinterpret_cast<const float4*>(Cb + 4 * j);
        const float4 k4 = *reinterpret_cast<const float4*>(kb + 4 * j);
        const float4 q4 = *reinterpret_cast<const float4*>(qb + 4 * j);
        float4 cn;
        cn.x = fmaf(fv, c4.x, vi * k4.x);
        cn.y = fmaf(fv, c4.y, vi * k4.y);
        cn.z = fmaf(fv, c4.z, vi * k4.z);
        cn.w = fmaf(fv, c4.w, vi * k4.w);
        *reinterpret_cast<float4*>(Cnb + 4 * j) = cn;
        dot = fmaf(cn.x, q4.x, dot);
        dot = fmaf(cn.y, q4.y, dot);
        dot = fmaf(cn.z, q4.z, dot);
        dot = fmaf(cn.w, q4.w, dot);
    }
    dot += __shfl_xor(dot, 1);
    dot += __shfl_xor(dot, 2);
    if (p == 0) ht[(size_t)b * D_ + i] = f2bf(dot * inv);
}

// ---------------------------------------------------------------------------
// K4: fused output via MFMA.  Tile 128x128; phase1 K=1024 (x@Wo^T),
// phase2 K=64 (ht@Wp^T); epilogue sigmoid*tanh.
// grid (8 col-panels, 128 M-tiles), block 256 (4 waves 2x2, each 64x64).
// ---------------------------------------------------------------------------
__global__ __launch_bounds__(256) void out_fused(
    const float* __restrict__ x, const ushort* __restrict__ Wo_b,
    const float* __restrict__ bo,
    const ushort* __restrict__ ht, const ushort* __restrict__ Wp_b,
    const float* __restrict__ bp,
    float* __restrict__ h_new)
{
    __shared__ __align__(16) ushort As[128][32];
    __shared__ __align__(16) ushort Bs[128][32];

    const int t = threadIdx.x;
    const int w = t >> 6, l = t & 63;
    const int wm = w >> 1, wn = w & 1;
    const int l4 = l >> 4, l15 = l & 15;
    const int mrow = blockIdx.y * 128;
    const int ncol = blockIdx.x * 128;

    const int srow = t >> 3;           // fp32 staging: 0..31
    const int skq  = (t & 7) * 4;
    const int rb   = t >> 2;           // bf16 staging: 0..63
    const int kb   = (t & 3) * 8;

    f32x4 acc_o[4][4] = {};
    f32x4 acc_p[4][4] = {};

    // ---- phase 1: K = 1024 over x (fp32->bf16) and Wo_b (bf16) ----
    for (int k0 = 0; k0 < IN_; k0 += 32) {
        __syncthreads();
        #pragma unroll
        for (int s = 0; s < 4; ++s) {
            const int r = srow + s * 32;
            const float4 g = *reinterpret_cast<const float4*>(
                &x[(size_t)(mrow + r) * IN_ + k0 + skq]);
            ushort p[4] = {f2bf(g.x), f2bf(g.y), f2bf(g.z), f2bf(g.w)};
            *reinterpret_cast<ushort4*>(&As[r][skq]) = *reinterpret_cast<ushort4*>(p);
        }
        #pragma unroll
        for (int s = 0; s < 2; ++s) {
            const int r = rb + s * 64;
            *reinterpret_cast<short8*>(&Bs[r][kb]) =
                *reinterpret_cast<const short8*>(&Wo_b[(size_t)(ncol + r) * IN_ + k0 + kb]);
        }
        __syncthreads();

        short8 af[4], bf_[4];
        #pragma unroll
        for (int m = 0; m < 4; ++m)
            af[m] = *reinterpret_cast<const short8*>(&As[wm * 64 + m * 16 + l15][l4 * 8]);
        #pragma unroll
        for (int n = 0; n < 4; ++n)
            bf_[n] = *reinterpret_cast<const short8*>(&Bs[wn * 64 + n * 16 + l15][l4 * 8]);
        #pragma unroll
        for (int m = 0; m < 4; ++m)
            #pragma unroll
            for (int n = 0; n < 4; ++n)
                acc_o[m][n] = mfma16x16x32(af[m], bf_[n], acc_o[m][n]);
    }

    // ---- phase 2: K = 64 over ht (bf16) and Wp_b (bf16) ----
    for (int k0 = 0; k0 < D_; k0 += 32) {
        __syncthreads();
        #pragma unroll
        for (int s = 0; s < 2; ++s) {
            const int r = rb + s * 64;
            *reinterpret_cast<short8*>(&As[r][kb]) =
                *reinterpret_cast<const short8*>(&ht[(size_t)(mrow + r) * D_ + k0 + kb]);
            *reinterpret_cast<short8*>(&Bs[r][kb]) =
                *reinterpret_cast<const short8*>(&Wp_b[(size_t)(ncol + r) * D_ + k0 + kb]);
        }
        __syncthreads();

        short8 af[4], bf_[4];
        #pragma unroll
        for (int m = 0; m < 4; ++m)
            af[m] = *reinterpret_cast<const short8*>(&As[wm * 64 + m * 16 + l15][l4 * 8]);
        #pragma unroll
        for (int n = 0; n < 4; ++n)
            bf_[n] = *reinterpret_cast<const short8*>(&Bs[wn * 64 + n * 16 + l15][l4 * 8]);
        #pragma unroll
        for (int m = 0; m < 4; ++m)
            #pragma unroll
            for (int n = 0; n < 4; ++n)
                acc_p[m][n] = mfma16x16x32(af[m], bf_[n], acc_p[m][n]);
    }

    // ---- epilogue: h = sigmoid(acc_o + bo) * tanh(acc_p + bp) ----
    #pragma unroll
    for (int n = 0; n < 4; ++n) {
        const int c = ncol + wn * 64 + n * 16 + l15;
        const float bov = bo[c];
        const float bpv = bp[c];
        #pragma unroll
        for (int m = 0; m < 4; ++m)
            #pragma unroll
            for (int r = 0; r < 4; ++r) {
                const int row = mrow + wm * 64 + m * 16 + l4 * 4 + r;
                const float o  = sigmoidf_(acc_o[m][n][r] + bov);
                const float th = tanhf_(acc_p[m][n][r] + bpv);
                h_new[(size_t)row * HID_ + c] = o * th;
            }
    }
}

// ---------------------------------------------------------------------------
extern "C" void kernel_launch(void* const* d_in, const int* in_sizes, int n_in,
                              void* d_out, int out_size, void* d_ws, size_t ws_size,
                              hipStream_t stream)
{
    (void)in_sizes; (void)n_in; (void)out_size; (void)ws_size;

    const float* x  = (const float*)d_in[0];
    const float* C  = (const float*)d_in[2];
    const float* n  = (const float*)d_in[3];
    const float* Wq = (const float*)d_in[4];
    const float* bq = (const float*)d_in[5];
    const float* Wk = (const float*)d_in[6];
    const float* bk = (const float*)d_in[7];
    const float* Wv = (const float*)d_in[8];
    const float* bv = (const float*)d_in[9];
    const float* Wi = (const float*)d_in[10];
    const float* bi = (const float*)d_in[11];
    const float* Wf = (const float*)d_in[12];
    const float* bf = (const float*)d_in[13];
    const float* Wo = (const float*)d_in[14];
    const float* bo = (const float*)d_in[15];
    const float* Wp = (const float*)d_in[16];
    const float* bp = (const float*)d_in[17];

    float* h_new = (float*)d_out;
    float* C_new = h_new + (size_t)B_ * HID_;
    float* n_new = C_new + (size_t)B_ * D_ * D_;

    // workspace layout (16.6 MB total; round-1 proved >= 16.8 MB available)
    float* ws = (float*)d_ws;
    float* q  = ws;                                   // 1M floats
    float* k  = q + (size_t)B_ * D_;                  // 1M floats
    float* v  = k + (size_t)B_ * D_;                  // 1M floats
    float* ig = v + (size_t)B_ * D_;                  // 16K floats
    float* fg = ig + B_;                              // 16K floats
    ushort* ht     = (ushort*)(fg + B_);              // 1M ushort (2 MB)
    ushort* Wqkv_b = ht + (size_t)B_ * D_;            // 196608 ushort
    ushort* Wo_b   = Wqkv_b + 196608;                 // 1048576 ushort
    ushort* Wp_b   = Wo_b + 1048576;                  // 65536 ushort

    cvt_w<<<dim3(1280), 256, 0, stream>>>(Wq, Wk, Wv, Wo, Wp, Wqkv_b, Wo_b, Wp_b);
    gates_if<<<dim3(B_ / 16), 256, 0, stream>>>(x, Wi, bi, Wf, bf, ig, fg);
    proj_qkv<<<dim3(B_ / 64), 256, 0, stream>>>(x, Wqkv_b, bq, bk, bv, q, k, v);
    cell_update<<<dim3(B_), 256, 0, stream>>>(C, q, k, v, ig, fg, n, C_new, n_new, ht);
    out_fused<<<dim3(HID_ / 128, B_ / 128), 256, 0, stream>>>(
        x, Wo_b, bo, ht, Wp_b, bp, h_new);
}

// Round 3
// 260.378 us; speedup vs baseline: 3.3912x; 1.1899x over previous
//
#include <hip/hip_runtime.h>
#include <hip/hip_bf16.h>
#include <math.h>

#define B_   16384
#define IN_  1024
#define HID_ 1024
#define D_   64

typedef float  f32x4  __attribute__((ext_vector_type(4)));
typedef short  short8 __attribute__((ext_vector_type(8)));
typedef __bf16 bf16x8 __attribute__((ext_vector_type(8)));

__device__ __forceinline__ unsigned short f2bf(float f) {
    unsigned u = __builtin_bit_cast(unsigned, f);
    u += 0x7fffu + ((u >> 16) & 1u);          // RTNE
    return (unsigned short)(u >> 16);
}

__device__ __forceinline__ f32x4 mfma16x16x32(short8 a, short8 b, f32x4 c) {
    return __builtin_amdgcn_mfma_f32_16x16x32_bf16(
        __builtin_bit_cast(bf16x8, a), __builtin_bit_cast(bf16x8, b), c, 0, 0, 0);
}

__device__ __forceinline__ float sigmoidf_(float x) { return 1.0f / (1.0f + __expf(-x)); }
__device__ __forceinline__ float tanhf_(float x) {
    x = fminf(fmaxf(x, -15.f), 15.f);
    float e = __expf(2.f * x);
    return (e - 1.f) / (e + 1.f);
}

// async global->LDS, 16B per lane, linear LDS dest (wave-uniform base + lane*16)
__device__ __forceinline__ void gload_lds16(const void* g, void* l) {
    __builtin_amdgcn_global_load_lds(
        (const __attribute__((address_space(1))) unsigned int*)g,
        (__attribute__((address_space(3))) unsigned int*)l, 16, 0, 0);
}

__device__ __forceinline__ short8 cvt8(float4 a, float4 b) {
    short8 r;
    r[0] = (short)f2bf(a.x); r[1] = (short)f2bf(a.y);
    r[2] = (short)f2bf(a.z); r[3] = (short)f2bf(a.w);
    r[4] = (short)f2bf(b.x); r[5] = (short)f2bf(b.y);
    r[6] = (short)f2bf(b.z); r[7] = (short)f2bf(b.w);
    return r;
}

// ===========================================================================
// FAST PATH (ws_size >= 51.1 MB)
// ===========================================================================

// K0f: convert x -> xb (bf16), and weights -> Wqkvif (256x1024 padded:
// rows 0-63 Wq, 64-127 Wk, 128-191 Wv, 192 Wi, 193 Wf, 194-255 zeros),
// Wo -> Wob, Wp -> Wpb.  grid 8864, block 256, 8 elems/thread.
__global__ __launch_bounds__(256) void cvt_f(
    const float* __restrict__ x,
    const float* __restrict__ Wq, const float* __restrict__ Wk,
    const float* __restrict__ Wv, const float* __restrict__ Wi,
    const float* __restrict__ Wf, const float* __restrict__ Wo,
    const float* __restrict__ Wp,
    ushort* __restrict__ xb, ushort* __restrict__ Wqkvif,
    ushort* __restrict__ Wob, ushort* __restrict__ Wpb)
{
    const int bid = blockIdx.x;
    const int t   = threadIdx.x;
    if (bid < 8192) {                       // x: 16,777,216 elems
        const size_t base = (size_t)bid * 2048 + (size_t)t * 8;
        const float4 g0 = *reinterpret_cast<const float4*>(&x[base]);
        const float4 g1 = *reinterpret_cast<const float4*>(&x[base + 4]);
        *reinterpret_cast<short8*>(&xb[base]) = cvt8(g0, g1);
    } else if (bid < 8320) {                // Wqkvif: 262,144 elems
        const int idx = (bid - 8192) * 2048 + t * 8;
        const int row = idx >> 10, col = idx & 1023;
        short8 o = {0, 0, 0, 0, 0, 0, 0, 0};
        const float* srcrow =
            (row < 64)  ? &Wq[(size_t)row * 1024] :
            (row < 128) ? &Wk[(size_t)(row - 64) * 1024] :
            (row < 192) ? &Wv[(size_t)(row - 128) * 1024] :
            (row == 192) ? Wi : (row == 193) ? Wf : nullptr;
        if (srcrow) {
            const float4 g0 = *reinterpret_cast<const float4*>(&srcrow[col]);
            const float4 g1 = *reinterpret_cast<const float4*>(&srcrow[col + 4]);
            o = cvt8(g0, g1);
        }
        *reinterpret_cast<short8*>(&Wqkvif[idx]) = o;
    } else if (bid < 8832) {                // Wo: 1,048,576 elems
        const size_t idx = (size_t)(bid - 8320) * 2048 + (size_t)t * 8;
        const float4 g0 = *reinterpret_cast<const float4*>(&Wo[idx]);
        const float4 g1 = *reinterpret_cast<const float4*>(&Wo[idx + 4]);
        *reinterpret_cast<short8*>(&Wob[idx]) = cvt8(g0, g1);
    } else {                                // Wp: 65,536 elems
        const int idx = (bid - 8832) * 2048 + t * 8;
        const float4 g0 = *reinterpret_cast<const float4*>(&Wp[idx]);
        const float4 g1 = *reinterpret_cast<const float4*>(&Wp[idx + 4]);
        *reinterpret_cast<short8*>(&Wpb[idx]) = cvt8(g0, g1);
    }
}

// K1f: fused qkv+gates GEMM.  Tile 64 rows x 256 cols (padded), BK=64.
// grid 256, block 256 (4 waves; wave w -> cols w*64..w*64+63).
// LDS tiles [rows][64] bf16, 16B-slot XOR-swizzled by (row&7); linear dest via
// inverse-swizzled global source (rule #21: same involution on source & read).
__global__ __launch_bounds__(256) void proj_gates_f(
    const ushort* __restrict__ xb, const ushort* __restrict__ Wqkvif,
    const float* __restrict__ bq, const float* __restrict__ bk,
    const float* __restrict__ bv, const float* __restrict__ bi,
    const float* __restrict__ bf,
    float* __restrict__ qo, float* __restrict__ ko, float* __restrict__ vo,
    float* __restrict__ ig, float* __restrict__ fg)
{
    __shared__ __align__(16) ushort As[64 * 64];
    __shared__ __align__(16) ushort Bs[256 * 64];

    const int t = threadIdx.x;
    const int w = t >> 6, l = t & 63;
    const int l4 = l >> 4, l15 = l & 15;
    const int mrow = blockIdx.x * 64;
    const int srow = t >> 3, sslot = t & 7;

    f32x4 acc[4][4] = {};

    for (int k0 = 0; k0 < IN_; k0 += 64) {
        __syncthreads();
        #pragma unroll
        for (int c = 0; c < 2; ++c) {
            const int r  = srow + 32 * c;
            const int gc = (sslot ^ (r & 7)) * 8;
            gload_lds16(&xb[(size_t)(mrow + r) * IN_ + k0 + gc],
                        &As[r * 64 + sslot * 8]);
        }
        #pragma unroll
        for (int c = 0; c < 8; ++c) {
            const int r  = srow + 32 * c;
            const int gc = (sslot ^ (r & 7)) * 8;
            gload_lds16(&Wqkvif[(size_t)r * IN_ + k0 + gc],
                        &Bs[r * 64 + sslot * 8]);
        }
        __syncthreads();

        #pragma unroll
        for (int kk = 0; kk < 2; ++kk) {
            short8 af[4], bfr[4];
            #pragma unroll
            for (int m = 0; m < 4; ++m) {
                const int R = m * 16 + l15;
                const int S = ((kk * 4 + l4) ^ (R & 7)) * 8;
                af[m] = *reinterpret_cast<const short8*>(&As[R * 64 + S]);
            }
            #pragma unroll
            for (int nn = 0; nn < 4; ++nn) {
                const int R = w * 64 + nn * 16 + l15;
                const int S = ((kk * 4 + l4) ^ (R & 7)) * 8;
                bfr[nn] = *reinterpret_cast<const short8*>(&Bs[R * 64 + S]);
            }
            #pragma unroll
            for (int m = 0; m < 4; ++m)
                #pragma unroll
                for (int nn = 0; nn < 4; ++nn)
                    acc[m][nn] = mfma16x16x32(af[m], bfr[nn], acc[m][nn]);
        }
    }

    #pragma unroll
    for (int nn = 0; nn < 4; ++nn) {
        const int c = w * 64 + nn * 16 + l15;
        if (c < 192) {
            const int mtx = c >> 6, lc = c & 63;
            float* __restrict__ out = (mtx == 0) ? qo : (mtx == 1) ? ko : vo;
            const float* __restrict__ bb = (mtx == 0) ? bq : (mtx == 1) ? bk : bv;
            const float bias = bb[lc];
            #pragma unroll
            for (int m = 0; m < 4; ++m)
                #pragma unroll
                for (int r = 0; r < 4; ++r)
                    out[(size_t)(mrow + m * 16 + l4 * 4 + r) * D_ + lc] =
                        acc[m][nn][r] + bias;
        } else if (c == 192) {
            #pragma unroll
            for (int m = 0; m < 4; ++m)
                #pragma unroll
                for (int r = 0; r < 4; ++r)
                    ig[mrow + m * 16 + l4 * 4 + r] = __expf(acc[m][nn][r] + bi[0]);
        } else if (c == 193) {
            #pragma unroll
            for (int m = 0; m < 4; ++m)
                #pragma unroll
                for (int r = 0; r < 4; ++r)
                    fg[mrow + m * 16 + l4 * 4 + r] = sigmoidf_(acc[m][nn][r] + bf[0]);
        }
    }
}

// K3: cell update (shared by both paths).  grid B, block 256.
__global__ __launch_bounds__(256) void cell_update(
    const float* __restrict__ C,
    const float* __restrict__ q, const float* __restrict__ k,
    const float* __restrict__ v,
    const float* __restrict__ ig, const float* __restrict__ fg,
    const float* __restrict__ n,
    float* __restrict__ C_new, float* __restrict__ n_new,
    ushort* __restrict__ ht)
{
    const int b = blockIdx.x;
    const int t = threadIdx.x;
    const int i = t >> 2;
    const int p = t & 3;

    const float iv = ig[b];
    const float fv = fg[b];
    const float nn = fv * n[b] + iv;
    if (t == 0) n_new[b] = nn;
    const float inv = 1.0f / (nn + 1e-8f);

    const float* __restrict__ qb  = q + (size_t)b * D_ + p * 16;
    const float* __restrict__ kb  = k + (size_t)b * D_ + p * 16;
    const float  vi = v[(size_t)b * D_ + i] * iv;
    const float* __restrict__ Cb  = C     + (size_t)b * D_ * D_ + i * D_ + p * 16;
    float* __restrict__       Cnb = C_new + (size_t)b * D_ * D_ + i * D_ + p * 16;

    float dot = 0.f;
    #pragma unroll
    for (int j = 0; j < 4; ++j) {
        const float4 c4 = *reinterpret_cast<const float4*>(Cb + 4 * j);
        const float4 k4 = *reinterpret_cast<const float4*>(kb + 4 * j);
        const float4 q4 = *reinterpret_cast<const float4*>(qb + 4 * j);
        float4 cn;
        cn.x = fmaf(fv, c4.x, vi * k4.x);
        cn.y = fmaf(fv, c4.y, vi * k4.y);
        cn.z = fmaf(fv, c4.z, vi * k4.z);
        cn.w = fmaf(fv, c4.w, vi * k4.w);
        *reinterpret_cast<float4*>(Cnb + 4 * j) = cn;
        dot = fmaf(cn.x, q4.x, dot);
        dot = fmaf(cn.y, q4.y, dot);
        dot = fmaf(cn.z, q4.z, dot);
        dot = fmaf(cn.w, q4.w, dot);
    }
    dot += __shfl_xor(dot, 1);
    dot += __shfl_xor(dot, 2);
    if (p == 0) ht[(size_t)b * D_ + i] = f2bf(dot * inv);
}

// K4f: fused output GEMM, m97-style.  128x128 tile, BK=64, global_load_lds,
// XOR-swizzled LDS.  phase1 x@Wo^T (K=1024), phase2 ht@Wp^T (K=64).
__global__ __launch_bounds__(256) void out_fused_f(
    const ushort* __restrict__ xb, const ushort* __restrict__ Wob,
    const float* __restrict__ bo,
    const ushort* __restrict__ ht, const ushort* __restrict__ Wpb,
    const float* __restrict__ bp,
    float* __restrict__ h_new)
{
    __shared__ __align__(16) ushort As[128 * 64];
    __shared__ __align__(16) ushort Bs[128 * 64];

    const int t = threadIdx.x;
    const int w = t >> 6, l = t & 63;
    const int wm = w >> 1, wn = w & 1;
    const int l4 = l >> 4, l15 = l & 15;
    const int mrow = blockIdx.y * 128;
    const int ncol = blockIdx.x * 128;
    const int srow = t >> 3, sslot = t & 7;

    f32x4 acc_o[4][4] = {};
    f32x4 acc_p[4][4] = {};

    // ---- phase 1: K = 1024 ----
    for (int k0 = 0; k0 < IN_; k0 += 64) {
        __syncthreads();
        #pragma unroll
        for (int c = 0; c < 4; ++c) {
            const int r  = srow + 32 * c;
            const int gc = (sslot ^ (r & 7)) * 8;
            gload_lds16(&xb[(size_t)(mrow + r) * IN_ + k0 + gc],
                        &As[r * 64 + sslot * 8]);
            gload_lds16(&Wob[(size_t)(ncol + r) * IN_ + k0 + gc],
                        &Bs[r * 64 + sslot * 8]);
        }
        __syncthreads();

        #pragma unroll
        for (int kk = 0; kk < 2; ++kk) {
            short8 af[4], bfr[4];
            #pragma unroll
            for (int m = 0; m < 4; ++m) {
                const int R = wm * 64 + m * 16 + l15;
                const int S = ((kk * 4 + l4) ^ (R & 7)) * 8;
                af[m] = *reinterpret_cast<const short8*>(&As[R * 64 + S]);
            }
            #pragma unroll
            for (int nn = 0; nn < 4; ++nn) {
                const int R = wn * 64 + nn * 16 + l15;
                const int S = ((kk * 4 + l4) ^ (R & 7)) * 8;
                bfr[nn] = *reinterpret_cast<const short8*>(&Bs[R * 64 + S]);
            }
            #pragma unroll
            for (int m = 0; m < 4; ++m)
                #pragma unroll
                for (int nn = 0; nn < 4; ++nn)
                    acc_o[m][nn] = mfma16x16x32(af[m], bfr[nn], acc_o[m][nn]);
        }
    }

    // ---- phase 2: K = 64 ----
    __syncthreads();
    #pragma unroll
    for (int c = 0; c < 4; ++c) {
        const int r  = srow + 32 * c;
        const int gc = (sslot ^ (r & 7)) * 8;
        gload_lds16(&ht[(size_t)(mrow + r) * D_ + gc],
                    &As[r * 64 + sslot * 8]);
        gload_lds16(&Wpb[(size_t)(ncol + r) * D_ + gc],
                    &Bs[r * 64 + sslot * 8]);
    }
    __syncthreads();
    #pragma unroll
    for (int kk = 0; kk < 2; ++kk) {
        short8 af[4], bfr[4];
        #pragma unroll
        for (int m = 0; m < 4; ++m) {
            const int R = wm * 64 + m * 16 + l15;
            const int S = ((kk * 4 + l4) ^ (R & 7)) * 8;
            af[m] = *reinterpret_cast<const short8*>(&As[R * 64 + S]);
        }
        #pragma unroll
        for (int nn = 0; nn < 4; ++nn) {
            const int R = wn * 64 + nn * 16 + l15;
            const int S = ((kk * 4 + l4) ^ (R & 7)) * 8;
            bfr[nn] = *reinterpret_cast<const short8*>(&Bs[R * 64 + S]);
        }
        #pragma unroll
        for (int m = 0; m < 4; ++m)
            #pragma unroll
            for (int nn = 0; nn < 4; ++nn)
                acc_p[m][nn] = mfma16x16x32(af[m], bfr[nn], acc_p[m][nn]);
    }

    // ---- epilogue ----
    #pragma unroll
    for (int nn = 0; nn < 4; ++nn) {
        const int c = ncol + wn * 64 + nn * 16 + l15;
        const float bov = bo[c];
        const float bpv = bp[c];
        #pragma unroll
        for (int m = 0; m < 4; ++m)
            #pragma unroll
            for (int r = 0; r < 4; ++r) {
                const int row = mrow + wm * 64 + m * 16 + l4 * 4 + r;
                h_new[(size_t)row * HID_ + c] =
                    sigmoidf_(acc_o[m][nn][r] + bov) * tanhf_(acc_p[m][nn][r] + bpv);
            }
    }
}

// ===========================================================================
// FALLBACK PATH (round-2 kernels, used when ws_size < 51.1 MB)
// ===========================================================================

__global__ __launch_bounds__(256) void cvt_w(
    const float* __restrict__ Wq, const float* __restrict__ Wk,
    const float* __restrict__ Wv, const float* __restrict__ Wo,
    const float* __restrict__ Wp,
    ushort* __restrict__ Wqkv_b, ushort* __restrict__ Wo_b, ushort* __restrict__ Wp_b)
{
    const size_t base = (size_t)blockIdx.x * 1024 + (size_t)threadIdx.x * 4;
    const float* src;  ushort* dst;
    if (base < 196608) {
        dst = Wqkv_b + base;
        src = (base < 65536) ? Wq + base
            : (base < 131072) ? Wk + (base - 65536)
                              : Wv + (base - 131072);
    } else if (base < 196608 + 1048576) {
        dst = Wo_b + (base - 196608);
        src = Wo   + (base - 196608);
    } else {
        dst = Wp_b + (base - 1245184);
        src = Wp   + (base - 1245184);
    }
    const float4 g = *reinterpret_cast<const float4*>(src);
    ushort4 o;
    o.x = f2bf(g.x); o.y = f2bf(g.y); o.z = f2bf(g.z); o.w = f2bf(g.w);
    *reinterpret_cast<ushort4*>(dst) = o;
}

__global__ __launch_bounds__(256) void proj_qkv(
    const float* __restrict__ x, const ushort* __restrict__ Wqkv_b,
    const float* __restrict__ bq, const float* __restrict__ bk, const float* __restrict__ bv,
    float* __restrict__ qo, float* __restrict__ ko, float* __restrict__ vo)
{
    __shared__ __align__(16) ushort As[64][32];
    __shared__ __align__(16) ushort Bs[192][32];

    const int t = threadIdx.x;
    const int w = t >> 6, l = t & 63;
    const int l4 = l >> 4, l15 = l & 15;
    const int mrow = blockIdx.x * 64;

    const int srow = t >> 3;
    const int skq  = (t & 7) * 4;
    const int rb   = t >> 2;
    const int kb   = (t & 3) * 8;

    f32x4 acc[4][3] = {};

    for (int k0 = 0; k0 < IN_; k0 += 32) {
        __syncthreads();
        #pragma unroll
        for (int s = 0; s < 2; ++s) {
            const int r = srow + s * 32;
            const float4 g = *reinterpret_cast<const float4*>(
                &x[(size_t)(mrow + r) * IN_ + k0 + skq]);
            ushort p[4] = {f2bf(g.x), f2bf(g.y), f2bf(g.z), f2bf(g.w)};
            *reinterpret_cast<ushort4*>(&As[r][skq]) = *reinterpret_cast<ushort4*>(p);
        }
        #pragma unroll
        for (int s = 0; s < 3; ++s) {
            const int r = rb + s * 64;
            *reinterpret_cast<short8*>(&Bs[r][kb]) =
                *reinterpret_cast<const short8*>(&Wqkv_b[(size_t)r * IN_ + k0 + kb]);
        }
        __syncthreads();

        short8 af[4], bf_[3];
        #pragma unroll
        for (int m = 0; m < 4; ++m)
            af[m] = *reinterpret_cast<const short8*>(&As[m * 16 + l15][l4 * 8]);
        #pragma unroll
        for (int nn = 0; nn < 3; ++nn)
            bf_[nn] = *reinterpret_cast<const short8*>(&Bs[w * 48 + nn * 16 + l15][l4 * 8]);
        #pragma unroll
        for (int m = 0; m < 4; ++m)
            #pragma unroll
            for (int nn = 0; nn < 3; ++nn)
                acc[m][nn] = mfma16x16x32(af[m], bf_[nn], acc[m][nn]);
    }

    #pragma unroll
    for (int nn = 0; nn < 3; ++nn) {
        const int c   = w * 48 + nn * 16 + l15;
        const int mtx = c >> 6, lc = c & 63;
        float* __restrict__ out = (mtx == 0) ? qo : (mtx == 1) ? ko : vo;
        const float* __restrict__ bb = (mtx == 0) ? bq : (mtx == 1) ? bk : bv;
        const float bias = bb[lc];
        #pragma unroll
        for (int m = 0; m < 4; ++m)
            #pragma unroll
            for (int r = 0; r < 4; ++r) {
                const int row = mrow + m * 16 + l4 * 4 + r;
                out[(size_t)row * D_ + lc] = acc[m][nn][r] + bias;
            }
    }
}

__global__ __launch_bounds__(256) void gates_if(
    const float* __restrict__ x,
    const float* __restrict__ Wi, const float* __restrict__ bi,
    const float* __restrict__ Wf, const float* __restrict__ bf,
    float* __restrict__ ig, float* __restrict__ fg)
{
    const int wave = threadIdx.x >> 6;
    const int lane = threadIdx.x & 63;
    const int row0 = blockIdx.x * 16 + wave * 4;

    for (int rr = 0; rr < 4; ++rr) {
        const int r = row0 + rr;
        const float* __restrict__ xr = x + (size_t)r * IN_;
        float si = 0.f, sf = 0.f;
        for (int k = lane; k < IN_; k += 64) {
            const float xv = xr[k];
            si = fmaf(xv, Wi[k], si);
            sf = fmaf(xv, Wf[k], sf);
        }
        #pragma unroll
        for (int off = 32; off > 0; off >>= 1) {
            si += __shfl_down(si, off);
            sf += __shfl_down(sf, off);
        }
        if (lane == 0) {
            ig[r] = __expf(si + bi[0]);
            fg[r] = sigmoidf_(sf + bf[0]);
        }
    }
}

__global__ __launch_bounds__(256) void out_fused(
    const float* __restrict__ x, const ushort* __restrict__ Wo_b,
    const float* __restrict__ bo,
    const ushort* __restrict__ ht, const ushort* __restrict__ Wp_b,
    const float* __restrict__ bp,
    float* __restrict__ h_new)
{
    __shared__ __align__(16) ushort As[128][32];
    __shared__ __align__(16) ushort Bs[128][32];

    const int t = threadIdx.x;
    const int w = t >> 6, l = t & 63;
    const int wm = w >> 1, wn = w & 1;
    const int l4 = l >> 4, l15 = l & 15;
    const int mrow = blockIdx.y * 128;
    const int ncol = blockIdx.x * 128;

    const int srow = t >> 3;
    const int skq  = (t & 7) * 4;
    const int rb   = t >> 2;
    const int kb   = (t & 3) * 8;

    f32x4 acc_o[4][4] = {};
    f32x4 acc_p[4][4] = {};

    for (int k0 = 0; k0 < IN_; k0 += 32) {
        __syncthreads();
        #pragma unroll
        for (int s = 0; s < 4; ++s) {
            const int r = srow + s * 32;
            const float4 g = *reinterpret_cast<const float4*>(
                &x[(size_t)(mrow + r) * IN_ + k0 + skq]);
            ushort p[4] = {f2bf(g.x), f2bf(g.y), f2bf(g.z), f2bf(g.w)};
            *reinterpret_cast<ushort4*>(&As[r][skq]) = *reinterpret_cast<ushort4*>(p);
        }
        #pragma unroll
        for (int s = 0; s < 2; ++s) {
            const int r = rb + s * 64;
            *reinterpret_cast<short8*>(&Bs[r][kb]) =
                *reinterpret_cast<const short8*>(&Wo_b[(size_t)(ncol + r) * IN_ + k0 + kb]);
        }
        __syncthreads();

        short8 af[4], bf_[4];
        #pragma unroll
        for (int m = 0; m < 4; ++m)
            af[m] = *reinterpret_cast<const short8*>(&As[wm * 64 + m * 16 + l15][l4 * 8]);
        #pragma unroll
        for (int nn = 0; nn < 4; ++nn)
            bf_[nn] = *reinterpret_cast<const short8*>(&Bs[wn * 64 + nn * 16 + l15][l4 * 8]);
        #pragma unroll
        for (int m = 0; m < 4; ++m)
            #pragma unroll
            for (int nn = 0; nn < 4; ++nn)
                acc_o[m][nn] = mfma16x16x32(af[m], bf_[nn], acc_o[m][nn]);
    }

    for (int k0 = 0; k0 < D_; k0 += 32) {
        __syncthreads();
        #pragma unroll
        for (int s = 0; s < 2; ++s) {
            const int r = rb + s * 64;
            *reinterpret_cast<short8*>(&As[r][kb]) =
                *reinterpret_cast<const short8*>(&ht[(size_t)(mrow + r) * D_ + k0 + kb]);
            *reinterpret_cast<short8*>(&Bs[r][kb]) =
                *reinterpret_cast<const short8*>(&Wp_b[(size_t)(ncol + r) * D_ + k0 + kb]);
        }
        __syncthreads();

        short8 af[4], bf_[4];
        #pragma unroll
        for (int m = 0; m < 4; ++m)
            af[m] = *reinterpret_cast<const short8*>(&As[wm * 64 + m * 16 + l15][l4 * 8]);
        #pragma unroll
        for (int nn = 0; nn < 4; ++nn)
            bf_[nn] = *reinterpret_cast<const short8*>(&Bs[wn * 64 + nn * 16 + l15][l4 * 8]);
        #pragma unroll
        for (int m = 0; m < 4; ++m)
            #pragma unroll
            for (int nn = 0; nn < 4; ++nn)
                acc_p[m][nn] = mfma16x16x32(af[m], bf_[nn], acc_p[m][nn]);
    }

    #pragma unroll
    for (int nn = 0; nn < 4; ++nn) {
        const int c = ncol + wn * 64 + nn * 16 + l15;
        const float bov = bo[c];
        const float bpv = bp[c];
        #pragma unroll
        for (int m = 0; m < 4; ++m)
            #pragma unroll
            for (int r = 0; r < 4; ++r) {
                const int row = mrow + wm * 64 + m * 16 + l4 * 4 + r;
                h_new[(size_t)row * HID_ + c] =
                    sigmoidf_(acc_o[m][nn][r] + bov) * tanhf_(acc_p[m][nn][r] + bpv);
            }
    }
}

// ---------------------------------------------------------------------------
extern "C" void kernel_launch(void* const* d_in, const int* in_sizes, int n_in,
                              void* d_out, int out_size, void* d_ws, size_t ws_size,
                              hipStream_t stream)
{
    (void)in_sizes; (void)n_in; (void)out_size;

    const float* x  = (const float*)d_in[0];
    const float* C  = (const float*)d_in[2];
    const float* n  = (const float*)d_in[3];
    const float* Wq = (const float*)d_in[4];
    const float* bq = (const float*)d_in[5];
    const float* Wk = (const float*)d_in[6];
    const float* bk = (const float*)d_in[7];
    const float* Wv = (const float*)d_in[8];
    const float* bv = (const float*)d_in[9];
    const float* Wi = (const float*)d_in[10];
    const float* bi = (const float*)d_in[11];
    const float* Wf = (const float*)d_in[12];
    const float* bf = (const float*)d_in[13];
    const float* Wo = (const float*)d_in[14];
    const float* bo = (const float*)d_in[15];
    const float* Wp = (const float*)d_in[16];
    const float* bp = (const float*)d_in[17];

    float* h_new = (float*)d_out;
    float* C_new = h_new + (size_t)B_ * HID_;
    float* n_new = C_new + (size_t)B_ * D_ * D_;

    if (ws_size >= 51118080ull) {
        // fast path: 51.1 MB workspace
        ushort* xb     = (ushort*)d_ws;                 // 16,777,216
        ushort* Wqkvif = xb + 16777216;                 //    262,144
        ushort* Wob    = Wqkvif + 262144;               //  1,048,576
        ushort* Wpb    = Wob + 1048576;                 //     65,536
        float*  q      = (float*)(Wpb + 65536);         //  1,048,576 f32
        float*  k      = q + 1048576;
        float*  v      = k + 1048576;
        float*  ig     = v + 1048576;                   //     16,384 f32
        float*  fg     = ig + 16384;
        ushort* ht     = (ushort*)(fg + 16384);         //  1,048,576

        cvt_f<<<dim3(8864), 256, 0, stream>>>(x, Wq, Wk, Wv, Wi, Wf, Wo, Wp,
                                              xb, Wqkvif, Wob, Wpb);
        proj_gates_f<<<dim3(B_ / 64), 256, 0, stream>>>(
            xb, Wqkvif, bq, bk, bv, bi, bf, q, k, v, ig, fg);
        cell_update<<<dim3(B_), 256, 0, stream>>>(C, q, k, v, ig, fg, n,
                                                  C_new, n_new, ht);
        out_fused_f<<<dim3(HID_ / 128, B_ / 128), 256, 0, stream>>>(
            xb, Wob, bo, ht, Wpb, bp, h_new);
    } else {
        // fallback: round-2 path (16.6 MB workspace)
        float* ws = (float*)d_ws;
        float* q  = ws;
        float* k  = q + (size_t)B_ * D_;
        float* v  = k + (size_t)B_ * D_;
        float* ig = v + (size_t)B_ * D_;
        float* fg = ig + B_;
        ushort* ht     = (ushort*)(fg + B_);
        ushort* Wqkv_b = ht + (size_t)B_ * D_;
        ushort* Wo_b   = Wqkv_b + 196608;
        ushort* Wp_b   = Wo_b + 1048576;

        cvt_w<<<dim3(1280), 256, 0, stream>>>(Wq, Wk, Wv, Wo, Wp, Wqkv_b, Wo_b, Wp_b);
        gates_if<<<dim3(B_ / 16), 256, 0, stream>>>(x, Wi, bi, Wf, bf, ig, fg);
        proj_qkv<<<dim3(B_ / 64), 256, 0, stream>>>(x, Wqkv_b, bq, bk, bv, q, k, v);
        cell_update<<<dim3(B_), 256, 0, stream>>>(C, q, k, v, ig, fg, n, C_new, n_new, ht);
        out_fused<<<dim3(HID_ / 128, B_ / 128), 256, 0, stream>>>(
            x, Wo_b, bo, ht, Wp_b, bp, h_new);
    }
}

// Round 4
// 254.025 us; speedup vs baseline: 3.4761x; 1.0250x over previous
//
#include <hip/hip_runtime.h>
#include <hip/hip_bf16.h>
#include <math.h>

#define B_   16384
#define IN_  1024
#define HID_ 1024
#define D_   64

typedef float  f32x4  __attribute__((ext_vector_type(4)));
typedef short  short8 __attribute__((ext_vector_type(8)));
typedef __bf16 bf16x8 __attribute__((ext_vector_type(8)));

__device__ __forceinline__ unsigned short f2bf(float f) {
    unsigned u = __builtin_bit_cast(unsigned, f);
    u += 0x7fffu + ((u >> 16) & 1u);          // RTNE
    return (unsigned short)(u >> 16);
}

__device__ __forceinline__ f32x4 mfma16x16x32(short8 a, short8 b, f32x4 c) {
    return __builtin_amdgcn_mfma_f32_16x16x32_bf16(
        __builtin_bit_cast(bf16x8, a), __builtin_bit_cast(bf16x8, b), c, 0, 0, 0);
}

__device__ __forceinline__ float sigmoidf_(float x) { return 1.0f / (1.0f + __expf(-x)); }
__device__ __forceinline__ float tanhf_(float x) {
    x = fminf(fmaxf(x, -15.f), 15.f);
    float e = __expf(2.f * x);
    return (e - 1.f) / (e + 1.f);
}

// async global->LDS, 16B per lane, linear LDS dest (wave-uniform base + lane*16)
__device__ __forceinline__ void gload_lds16(const void* g, void* l) {
    __builtin_amdgcn_global_load_lds(
        (const __attribute__((address_space(1))) unsigned int*)g,
        (__attribute__((address_space(3))) unsigned int*)l, 16, 0, 0);
}

__device__ __forceinline__ short8 cvt8(float4 a, float4 b) {
    short8 r;
    r[0] = (short)f2bf(a.x); r[1] = (short)f2bf(a.y);
    r[2] = (short)f2bf(a.z); r[3] = (short)f2bf(a.w);
    r[4] = (short)f2bf(b.x); r[5] = (short)f2bf(b.y);
    r[6] = (short)f2bf(b.z); r[7] = (short)f2bf(b.w);
    return r;
}

// ===========================================================================
// FAST PATH (ws_size >= 38.5 MB)
// ===========================================================================

// K0: weights-only bf16 conversion.
// Wqkvif (256x1024 padded: 0-63 Wq, 64-127 Wk, 128-191 Wv, 192 Wi, 193 Wf,
// 194-255 zeros), Wob (1024x1024), Wpb (1024x64).  grid 672, block 256.
__global__ __launch_bounds__(256) void cvt_w2(
    const float* __restrict__ Wq, const float* __restrict__ Wk,
    const float* __restrict__ Wv, const float* __restrict__ Wi,
    const float* __restrict__ Wf, const float* __restrict__ Wo,
    const float* __restrict__ Wp,
    ushort* __restrict__ Wqkvif, ushort* __restrict__ Wob,
    ushort* __restrict__ Wpb)
{
    const int bid = blockIdx.x;
    const int t   = threadIdx.x;
    if (bid < 128) {                        // Wqkvif: 262,144 elems
        const int idx = bid * 2048 + t * 8;
        const int row = idx >> 10, col = idx & 1023;
        short8 o = {0, 0, 0, 0, 0, 0, 0, 0};
        const float* srcrow =
            (row < 64)  ? &Wq[(size_t)row * 1024] :
            (row < 128) ? &Wk[(size_t)(row - 64) * 1024] :
            (row < 192) ? &Wv[(size_t)(row - 128) * 1024] :
            (row == 192) ? Wi : (row == 193) ? Wf : nullptr;
        if (srcrow) {
            const float4 g0 = *reinterpret_cast<const float4*>(&srcrow[col]);
            const float4 g1 = *reinterpret_cast<const float4*>(&srcrow[col + 4]);
            o = cvt8(g0, g1);
        }
        *reinterpret_cast<short8*>(&Wqkvif[idx]) = o;
    } else if (bid < 640) {                 // Wob: 1,048,576 elems
        const size_t idx = (size_t)(bid - 128) * 2048 + (size_t)t * 8;
        const float4 g0 = *reinterpret_cast<const float4*>(&Wo[idx]);
        const float4 g1 = *reinterpret_cast<const float4*>(&Wo[idx + 4]);
        *reinterpret_cast<short8*>(&Wob[idx]) = cvt8(g0, g1);
    } else {                                // Wpb: 65,536 elems
        const int idx = (bid - 640) * 2048 + t * 8;
        const float4 g0 = *reinterpret_cast<const float4*>(&Wp[idx]);
        const float4 g1 = *reinterpret_cast<const float4*>(&Wp[idx + 4]);
        *reinterpret_cast<short8*>(&Wpb[idx]) = cvt8(g0, g1);
    }
}

// K1: fused projection + gates + cell update.
// Per block: 32 batch rows.  GEMM x(32xK)@Wqkvif^T(256xK) -> q/k/v/i/f in LDS
// panel P; x is converted to bf16 on the fly and also written to global xb.
// Then cell update: C_new = f*C + i*v(x)k, n_new = f*n + i,
// ht = (C_new@q)/(n_new+1e-8) (bf16).  grid 512, block 256.
__global__ __launch_bounds__(256) void proj_cell_f(
    const float* __restrict__ x, const ushort* __restrict__ Wqkvif,
    const float* __restrict__ bq, const float* __restrict__ bk,
    const float* __restrict__ bv, const float* __restrict__ bi,
    const float* __restrict__ bf,
    const float* __restrict__ C, const float* __restrict__ n,
    ushort* __restrict__ xb, float* __restrict__ C_new,
    float* __restrict__ n_new, ushort* __restrict__ ht)
{
    __shared__ __align__(16) ushort As[32 * 64];    //  4 KB, XOR-swizzled
    __shared__ __align__(16) ushort Bs[256 * 64];   // 32 KB, XOR-swizzled
    __shared__ __align__(16) float  P[32][196];     // 24.5 KB q|k|v|ig|fg

    const int t = threadIdx.x;
    const int w = t >> 6, l = t & 63;
    const int l4 = l >> 4, l15 = l & 15;
    const int mrow = blockIdx.x * 32;
    const int sr = t >> 3, ss = t & 7;     // staging: row 0..31, 16B slot 0..7

    f32x4 acc[2][4] = {};

    for (int k0 = 0; k0 < IN_; k0 += 64) {
        __syncthreads();
        // A: x fp32 -> bf16 regs -> swizzled LDS write + linear global xb
        {
            const size_t gx = (size_t)(mrow + sr) * IN_ + k0 + ss * 8;
            const float4 g0 = *reinterpret_cast<const float4*>(&x[gx]);
            const float4 g1 = *reinterpret_cast<const float4*>(&x[gx + 4]);
            const short8 vv = cvt8(g0, g1);
            *reinterpret_cast<short8*>(&As[sr * 64 + ((ss ^ (sr & 7)) * 8)]) = vv;
            *reinterpret_cast<short8*>(&xb[gx]) = vv;
        }
        // B: Wqkvif via global_load_lds, inverse-swizzled source (rule #21)
        #pragma unroll
        for (int c = 0; c < 8; ++c) {
            const int r  = sr + 32 * c;
            const int gc = (ss ^ (r & 7)) * 8;
            gload_lds16(&Wqkvif[(size_t)r * IN_ + k0 + gc],
                        &Bs[r * 64 + ss * 8]);
        }
        __syncthreads();

        #pragma unroll
        for (int kk = 0; kk < 2; ++kk) {
            short8 af[2], bfr[4];
            #pragma unroll
            for (int m = 0; m < 2; ++m) {
                const int R = m * 16 + l15;
                const int S = ((kk * 4 + l4) ^ (R & 7)) * 8;
                af[m] = *reinterpret_cast<const short8*>(&As[R * 64 + S]);
            }
            #pragma unroll
            for (int nn = 0; nn < 4; ++nn) {
                const int R = w * 64 + nn * 16 + l15;
                const int S = ((kk * 4 + l4) ^ (R & 7)) * 8;
                bfr[nn] = *reinterpret_cast<const short8*>(&Bs[R * 64 + S]);
            }
            #pragma unroll
            for (int m = 0; m < 2; ++m)
                #pragma unroll
                for (int nn = 0; nn < 4; ++nn)
                    acc[m][nn] = mfma16x16x32(af[m], bfr[nn], acc[m][nn]);
        }
    }

    // ---- epilogue: scatter q/k/v (+bias) and activated gates into P ----
    #pragma unroll
    for (int nn = 0; nn < 4; ++nn) {
        const int c = w * 64 + nn * 16 + l15;
        if (c < 192) {
            const float bias = (c < 64) ? bq[c] : (c < 128) ? bk[c - 64] : bv[c - 128];
            #pragma unroll
            for (int m = 0; m < 2; ++m)
                #pragma unroll
                for (int r = 0; r < 4; ++r)
                    P[m * 16 + l4 * 4 + r][c] = acc[m][nn][r] + bias;
        } else if (c == 192) {
            #pragma unroll
            for (int m = 0; m < 2; ++m)
                #pragma unroll
                for (int r = 0; r < 4; ++r)
                    P[m * 16 + l4 * 4 + r][192] = __expf(acc[m][nn][r] + bi[0]);
        } else if (c == 193) {
            #pragma unroll
            for (int m = 0; m < 2; ++m)
                #pragma unroll
                for (int r = 0; r < 4; ++r)
                    P[m * 16 + l4 * 4 + r][193] = sigmoidf_(acc[m][nn][r] + bf[0]);
        }
    }
    __syncthreads();

    // ---- cell phase: thread t -> batch row b = t>>3, col-octant p = t&7 ----
    {
        const int b = t >> 3, p = t & 7;
        float q8[8], k8[8];
        #pragma unroll
        for (int j = 0; j < 8; ++j) {
            q8[j] = P[b][p * 8 + j];
            k8[j] = P[b][64 + p * 8 + j];
        }
        const float ig = P[b][192];
        const float fg = P[b][193];
        const float nn_ = fg * n[mrow + b] + ig;
        if (p == 0) n_new[mrow + b] = nn_;
        const float inv = 1.0f / (nn_ + 1e-8f);

        const float* __restrict__ Cg  = C     + (size_t)(mrow + b) * 4096 + p * 8;
        float* __restrict__       Cng = C_new + (size_t)(mrow + b) * 4096 + p * 8;
        ushort* __restrict__      htb = ht + (size_t)(mrow + b) * 64;

        #pragma unroll 4
        for (int i = 0; i < 64; ++i) {
            const float vi = ig * P[b][128 + i];
            const float4 c0 = *reinterpret_cast<const float4*>(Cg + (size_t)i * 64);
            const float4 c1 = *reinterpret_cast<const float4*>(Cg + (size_t)i * 64 + 4);
            float4 n0, n1;
            n0.x = fmaf(fg, c0.x, vi * k8[0]);
            n0.y = fmaf(fg, c0.y, vi * k8[1]);
            n0.z = fmaf(fg, c0.z, vi * k8[2]);
            n0.w = fmaf(fg, c0.w, vi * k8[3]);
            n1.x = fmaf(fg, c1.x, vi * k8[4]);
            n1.y = fmaf(fg, c1.y, vi * k8[5]);
            n1.z = fmaf(fg, c1.z, vi * k8[6]);
            n1.w = fmaf(fg, c1.w, vi * k8[7]);
            *reinterpret_cast<float4*>(Cng + (size_t)i * 64)     = n0;
            *reinterpret_cast<float4*>(Cng + (size_t)i * 64 + 4) = n1;
            float part = n0.x * q8[0];
            part = fmaf(n0.y, q8[1], part);
            part = fmaf(n0.z, q8[2], part);
            part = fmaf(n0.w, q8[3], part);
            part = fmaf(n1.x, q8[4], part);
            part = fmaf(n1.y, q8[5], part);
            part = fmaf(n1.z, q8[6], part);
            part = fmaf(n1.w, q8[7], part);
            part += __shfl_xor(part, 1);
            part += __shfl_xor(part, 2);
            part += __shfl_xor(part, 4);
            if (p == 0) htb[i] = f2bf(part * inv);
        }
    }
}

// K2: fused output GEMM (unchanged round-3 kernel, proven).
// 128x128 tile, BK=64, global_load_lds, XOR-swizzled LDS.
// phase1 xb@Wob^T (K=1024), phase2 ht@Wpb^T (K=64), sigmoid*tanh epilogue.
__global__ __launch_bounds__(256) void out_fused_f(
    const ushort* __restrict__ xb, const ushort* __restrict__ Wob,
    const float* __restrict__ bo,
    const ushort* __restrict__ ht, const ushort* __restrict__ Wpb,
    const float* __restrict__ bp,
    float* __restrict__ h_new)
{
    __shared__ __align__(16) ushort As[128 * 64];
    __shared__ __align__(16) ushort Bs[128 * 64];

    const int t = threadIdx.x;
    const int w = t >> 6, l = t & 63;
    const int wm = w >> 1, wn = w & 1;
    const int l4 = l >> 4, l15 = l & 15;
    const int mrow = blockIdx.y * 128;
    const int ncol = blockIdx.x * 128;
    const int srow = t >> 3, sslot = t & 7;

    f32x4 acc_o[4][4] = {};
    f32x4 acc_p[4][4] = {};

    for (int k0 = 0; k0 < IN_; k0 += 64) {
        __syncthreads();
        #pragma unroll
        for (int c = 0; c < 4; ++c) {
            const int r  = srow + 32 * c;
            const int gc = (sslot ^ (r & 7)) * 8;
            gload_lds16(&xb[(size_t)(mrow + r) * IN_ + k0 + gc],
                        &As[r * 64 + sslot * 8]);
            gload_lds16(&Wob[(size_t)(ncol + r) * IN_ + k0 + gc],
                        &Bs[r * 64 + sslot * 8]);
        }
        __syncthreads();

        #pragma unroll
        for (int kk = 0; kk < 2; ++kk) {
            short8 af[4], bfr[4];
            #pragma unroll
            for (int m = 0; m < 4; ++m) {
                const int R = wm * 64 + m * 16 + l15;
                const int S = ((kk * 4 + l4) ^ (R & 7)) * 8;
                af[m] = *reinterpret_cast<const short8*>(&As[R * 64 + S]);
            }
            #pragma unroll
            for (int nn = 0; nn < 4; ++nn) {
                const int R = wn * 64 + nn * 16 + l15;
                const int S = ((kk * 4 + l4) ^ (R & 7)) * 8;
                bfr[nn] = *reinterpret_cast<const short8*>(&Bs[R * 64 + S]);
            }
            #pragma unroll
            for (int m = 0; m < 4; ++m)
                #pragma unroll
                for (int nn = 0; nn < 4; ++nn)
                    acc_o[m][nn] = mfma16x16x32(af[m], bfr[nn], acc_o[m][nn]);
        }
    }

    __syncthreads();
    #pragma unroll
    for (int c = 0; c < 4; ++c) {
        const int r  = srow + 32 * c;
        const int gc = (sslot ^ (r & 7)) * 8;
        gload_lds16(&ht[(size_t)(mrow + r) * D_ + gc],
                    &As[r * 64 + sslot * 8]);
        gload_lds16(&Wpb[(size_t)(ncol + r) * D_ + gc],
                    &Bs[r * 64 + sslot * 8]);
    }
    __syncthreads();
    #pragma unroll
    for (int kk = 0; kk < 2; ++kk) {
        short8 af[4], bfr[4];
        #pragma unroll
        for (int m = 0; m < 4; ++m) {
            const int R = wm * 64 + m * 16 + l15;
            const int S = ((kk * 4 + l4) ^ (R & 7)) * 8;
            af[m] = *reinterpret_cast<const short8*>(&As[R * 64 + S]);
        }
        #pragma unroll
        for (int nn = 0; nn < 4; ++nn) {
            const int R = wn * 64 + nn * 16 + l15;
            const int S = ((kk * 4 + l4) ^ (R & 7)) * 8;
            bfr[nn] = *reinterpret_cast<const short8*>(&Bs[R * 64 + S]);
        }
        #pragma unroll
        for (int m = 0; m < 4; ++m)
            #pragma unroll
            for (int nn = 0; nn < 4; ++nn)
                acc_p[m][nn] = mfma16x16x32(af[m], bfr[nn], acc_p[m][nn]);
    }

    #pragma unroll
    for (int nn = 0; nn < 4; ++nn) {
        const int c = ncol + wn * 64 + nn * 16 + l15;
        const float bov = bo[c];
        const float bpv = bp[c];
        #pragma unroll
        for (int m = 0; m < 4; ++m)
            #pragma unroll
            for (int r = 0; r < 4; ++r) {
                const int row = mrow + wm * 64 + m * 16 + l4 * 4 + r;
                h_new[(size_t)row * HID_ + c] =
                    sigmoidf_(acc_o[m][nn][r] + bov) * tanhf_(acc_p[m][nn][r] + bpv);
            }
    }
}

// ===========================================================================
// FALLBACK PATH (round-2 kernels, used when ws_size < 38.5 MB)
// ===========================================================================

__global__ __launch_bounds__(256) void cvt_w(
    const float* __restrict__ Wq, const float* __restrict__ Wk,
    const float* __restrict__ Wv, const float* __restrict__ Wo,
    const float* __restrict__ Wp,
    ushort* __restrict__ Wqkv_b, ushort* __restrict__ Wo_b, ushort* __restrict__ Wp_b)
{
    const size_t base = (size_t)blockIdx.x * 1024 + (size_t)threadIdx.x * 4;
    const float* src;  ushort* dst;
    if (base < 196608) {
        dst = Wqkv_b + base;
        src = (base < 65536) ? Wq + base
            : (base < 131072) ? Wk + (base - 65536)
                              : Wv + (base - 131072);
    } else if (base < 196608 + 1048576) {
        dst = Wo_b + (base - 196608);
        src = Wo   + (base - 196608);
    } else {
        dst = Wp_b + (base - 1245184);
        src = Wp   + (base - 1245184);
    }
    const float4 g = *reinterpret_cast<const float4*>(src);
    ushort4 o;
    o.x = f2bf(g.x); o.y = f2bf(g.y); o.z = f2bf(g.z); o.w = f2bf(g.w);
    *reinterpret_cast<ushort4*>(dst) = o;
}

__global__ __launch_bounds__(256) void proj_qkv(
    const float* __restrict__ x, const ushort* __restrict__ Wqkv_b,
    const float* __restrict__ bq, const float* __restrict__ bk, const float* __restrict__ bv,
    float* __restrict__ qo, float* __restrict__ ko, float* __restrict__ vo)
{
    __shared__ __align__(16) ushort As[64][32];
    __shared__ __align__(16) ushort Bs[192][32];

    const int t = threadIdx.x;
    const int w = t >> 6, l = t & 63;
    const int l4 = l >> 4, l15 = l & 15;
    const int mrow = blockIdx.x * 64;

    const int srow = t >> 3;
    const int skq  = (t & 7) * 4;
    const int rb   = t >> 2;
    const int kb   = (t & 3) * 8;

    f32x4 acc[4][3] = {};

    for (int k0 = 0; k0 < IN_; k0 += 32) {
        __syncthreads();
        #pragma unroll
        for (int s = 0; s < 2; ++s) {
            const int r = srow + s * 32;
            const float4 g = *reinterpret_cast<const float4*>(
                &x[(size_t)(mrow + r) * IN_ + k0 + skq]);
            ushort p[4] = {f2bf(g.x), f2bf(g.y), f2bf(g.z), f2bf(g.w)};
            *reinterpret_cast<ushort4*>(&As[r][skq]) = *reinterpret_cast<ushort4*>(p);
        }
        #pragma unroll
        for (int s = 0; s < 3; ++s) {
            const int r = rb + s * 64;
            *reinterpret_cast<short8*>(&Bs[r][kb]) =
                *reinterpret_cast<const short8*>(&Wqkv_b[(size_t)r * IN_ + k0 + kb]);
        }
        __syncthreads();

        short8 af[4], bf_[3];
        #pragma unroll
        for (int m = 0; m < 4; ++m)
            af[m] = *reinterpret_cast<const short8*>(&As[m * 16 + l15][l4 * 8]);
        #pragma unroll
        for (int nn = 0; nn < 3; ++nn)
            bf_[nn] = *reinterpret_cast<const short8*>(&Bs[w * 48 + nn * 16 + l15][l4 * 8]);
        #pragma unroll
        for (int m = 0; m < 4; ++m)
            #pragma unroll
            for (int nn = 0; nn < 3; ++nn)
                acc[m][nn] = mfma16x16x32(af[m], bf_[nn], acc[m][nn]);
    }

    #pragma unroll
    for (int nn = 0; nn < 3; ++nn) {
        const int c   = w * 48 + nn * 16 + l15;
        const int mtx = c >> 6, lc = c & 63;
        float* __restrict__ out = (mtx == 0) ? qo : (mtx == 1) ? ko : vo;
        const float* __restrict__ bb = (mtx == 0) ? bq : (mtx == 1) ? bk : bv;
        const float bias = bb[lc];
        #pragma unroll
        for (int m = 0; m < 4; ++m)
            #pragma unroll
            for (int r = 0; r < 4; ++r) {
                const int row = mrow + m * 16 + l4 * 4 + r;
                out[(size_t)row * D_ + lc] = acc[m][nn][r] + bias;
            }
    }
}

__global__ __launch_bounds__(256) void gates_if(
    const float* __restrict__ x,
    const float* __restrict__ Wi, const float* __restrict__ bi,
    const float* __restrict__ Wf, const float* __restrict__ bf,
    float* __restrict__ ig, float* __restrict__ fg)
{
    const int wave = threadIdx.x >> 6;
    const int lane = threadIdx.x & 63;
    const int row0 = blockIdx.x * 16 + wave * 4;

    for (int rr = 0; rr < 4; ++rr) {
        const int r = row0 + rr;
        const float* __restrict__ xr = x + (size_t)r * IN_;
        float si = 0.f, sf = 0.f;
        for (int k = lane; k < IN_; k += 64) {
            const float xv = xr[k];
            si = fmaf(xv, Wi[k], si);
            sf = fmaf(xv, Wf[k], sf);
        }
        #pragma unroll
        for (int off = 32; off > 0; off >>= 1) {
            si += __shfl_down(si, off);
            sf += __shfl_down(sf, off);
        }
        if (lane == 0) {
            ig[r] = __expf(si + bi[0]);
            fg[r] = sigmoidf_(sf + bf[0]);
        }
    }
}

__global__ __launch_bounds__(256) void cell_update(
    const float* __restrict__ C,
    const float* __restrict__ q, const float* __restrict__ k,
    const float* __restrict__ v,
    const float* __restrict__ ig, const float* __restrict__ fg,
    const float* __restrict__ n,
    float* __restrict__ C_new, float* __restrict__ n_new,
    ushort* __restrict__ ht)
{
    const int b = blockIdx.x;
    const int t = threadIdx.x;
    const int i = t >> 2;
    const int p = t & 3;

    const float iv = ig[b];
    const float fv = fg[b];
    const float nn = fv * n[b] + iv;
    if (t == 0) n_new[b] = nn;
    const float inv = 1.0f / (nn + 1e-8f);

    const float* __restrict__ qb  = q + (size_t)b * D_ + p * 16;
    const float* __restrict__ kb  = k + (size_t)b * D_ + p * 16;
    const float  vi = v[(size_t)b * D_ + i] * iv;
    const float* __restrict__ Cb  = C     + (size_t)b * D_ * D_ + i * D_ + p * 16;
    float* __restrict__       Cnb = C_new + (size_t)b * D_ * D_ + i * D_ + p * 16;

    float dot = 0.f;
    #pragma unroll
    for (int j = 0; j < 4; ++j) {
        const float4 c4 = *reinterpret_cast<const float4*>(Cb + 4 * j);
        const float4 k4 = *reinterpret_cast<const float4*>(kb + 4 * j);
        const float4 q4 = *reinterpret_cast<const float4*>(qb + 4 * j);
        float4 cn;
        cn.x = fmaf(fv, c4.x, vi * k4.x);
        cn.y = fmaf(fv, c4.y, vi * k4.y);
        cn.z = fmaf(fv, c4.z, vi * k4.z);
        cn.w = fmaf(fv, c4.w, vi * k4.w);
        *reinterpret_cast<float4*>(Cnb + 4 * j) = cn;
        dot = fmaf(cn.x, q4.x, dot);
        dot = fmaf(cn.y, q4.y, dot);
        dot = fmaf(cn.z, q4.z, dot);
        dot = fmaf(cn.w, q4.w, dot);
    }
    dot += __shfl_xor(dot, 1);
    dot += __shfl_xor(dot, 2);
    if (p == 0) ht[(size_t)b * D_ + i] = f2bf(dot * inv);
}

__global__ __launch_bounds__(256) void out_fused(
    const float* __restrict__ x, const ushort* __restrict__ Wo_b,
    const float* __restrict__ bo,
    const ushort* __restrict__ ht, const ushort* __restrict__ Wp_b,
    const float* __restrict__ bp,
    float* __restrict__ h_new)
{
    __shared__ __align__(16) ushort As[128][32];
    __shared__ __align__(16) ushort Bs[128][32];

    const int t = threadIdx.x;
    const int w = t >> 6, l = t & 63;
    const int wm = w >> 1, wn = w & 1;
    const int l4 = l >> 4, l15 = l & 15;
    const int mrow = blockIdx.y * 128;
    const int ncol = blockIdx.x * 128;

    const int srow = t >> 3;
    const int skq  = (t & 7) * 4;
    const int rb   = t >> 2;
    const int kb   = (t & 3) * 8;

    f32x4 acc_o[4][4] = {};
    f32x4 acc_p[4][4] = {};

    for (int k0 = 0; k0 < IN_; k0 += 32) {
        __syncthreads();
        #pragma unroll
        for (int s = 0; s < 4; ++s) {
            const int r = srow + s * 32;
            const float4 g = *reinterpret_cast<const float4*>(
                &x[(size_t)(mrow + r) * IN_ + k0 + skq]);
            ushort p[4] = {f2bf(g.x), f2bf(g.y), f2bf(g.z), f2bf(g.w)};
            *reinterpret_cast<ushort4*>(&As[r][skq]) = *reinterpret_cast<ushort4*>(p);
        }
        #pragma unroll
        for (int s = 0; s < 2; ++s) {
            const int r = rb + s * 64;
            *reinterpret_cast<short8*>(&Bs[r][kb]) =
                *reinterpret_cast<const short8*>(&Wo_b[(size_t)(ncol + r) * IN_ + k0 + kb]);
        }
        __syncthreads();

        short8 af[4], bf_[4];
        #pragma unroll
        for (int m = 0; m < 4; ++m)
            af[m] = *reinterpret_cast<const short8*>(&As[wm * 64 + m * 16 + l15][l4 * 8]);
        #pragma unroll
        for (int nn = 0; nn < 4; ++nn)
            bf_[nn] = *reinterpret_cast<const short8*>(&Bs[wn * 64 + nn * 16 + l15][l4 * 8]);
        #pragma unroll
        for (int m = 0; m < 4; ++m)
            #pragma unroll
            for (int nn = 0; nn < 4; ++nn)
                acc_o[m][nn] = mfma16x16x32(af[m], bf_[nn], acc_o[m][nn]);
    }

    for (int k0 = 0; k0 < D_; k0 += 32) {
        __syncthreads();
        #pragma unroll
        for (int s = 0; s < 2; ++s) {
            const int r = rb + s * 64;
            *reinterpret_cast<short8*>(&As[r][kb]) =
                *reinterpret_cast<const short8*>(&ht[(size_t)(mrow + r) * D_ + k0 + kb]);
            *reinterpret_cast<short8*>(&Bs[r][kb]) =
                *reinterpret_cast<const short8*>(&Wp_b[(size_t)(ncol + r) * D_ + k0 + kb]);
        }
        __syncthreads();

        short8 af[4], bf_[4];
        #pragma unroll
        for (int m = 0; m < 4; ++m)
            af[m] = *reinterpret_cast<const short8*>(&As[wm * 64 + m * 16 + l15][l4 * 8]);
        #pragma unroll
        for (int nn = 0; nn < 4; ++nn)
            bf_[nn] = *reinterpret_cast<const short8*>(&Bs[wn * 64 + nn * 16 + l15][l4 * 8]);
        #pragma unroll
        for (int m = 0; m < 4; ++m)
            #pragma unroll
            for (int nn = 0; nn < 4; ++nn)
                acc_p[m][nn] = mfma16x16x32(af[m], bf_[nn], acc_p[m][nn]);
    }

    #pragma unroll
    for (int nn = 0; nn < 4; ++nn) {
        const int c = ncol + wn * 64 + nn * 16 + l15;
        const float bov = bo[c];
        const float bpv = bp[c];
        #pragma unroll
        for (int m = 0; m < 4; ++m)
            #pragma unroll
            for (int r = 0; r < 4; ++r) {
                const int row = mrow + wm * 64 + m * 16 + l4 * 4 + r;
                h_new[(size_t)row * HID_ + c] =
                    sigmoidf_(acc_o[m][nn][r] + bov) * tanhf_(acc_p[m][nn][r] + bpv);
            }
    }
}

// ---------------------------------------------------------------------------
extern "C" void kernel_launch(void* const* d_in, const int* in_sizes, int n_in,
                              void* d_out, int out_size, void* d_ws, size_t ws_size,
                              hipStream_t stream)
{
    (void)in_sizes; (void)n_in; (void)out_size;

    const float* x  = (const float*)d_in[0];
    const float* C  = (const float*)d_in[2];
    const float* n  = (const float*)d_in[3];
    const float* Wq = (const float*)d_in[4];
    const float* bq = (const float*)d_in[5];
    const float* Wk = (const float*)d_in[6];
    const float* bk = (const float*)d_in[7];
    const float* Wv = (const float*)d_in[8];
    const float* bv = (const float*)d_in[9];
    const float* Wi = (const float*)d_in[10];
    const float* bi = (const float*)d_in[11];
    const float* Wf = (const float*)d_in[12];
    const float* bf = (const float*)d_in[13];
    const float* Wo = (const float*)d_in[14];
    const float* bo = (const float*)d_in[15];
    const float* Wp = (const float*)d_in[16];
    const float* bp = (const float*)d_in[17];

    float* h_new = (float*)d_out;
    float* C_new = h_new + (size_t)B_ * HID_;
    float* n_new = C_new + (size_t)B_ * D_ * D_;

    if (ws_size >= 38500000ull) {
        // fast path (~38.5 MB workspace)
        ushort* xb     = (ushort*)d_ws;                 // 16,777,216
        ushort* Wqkvif = xb + 16777216;                 //    262,144
        ushort* Wob    = Wqkvif + 262144;               //  1,048,576
        ushort* Wpb    = Wob + 1048576;                 //     65,536
        ushort* ht     = Wpb + 65536;                   //  1,048,576

        cvt_w2<<<dim3(672), 256, 0, stream>>>(Wq, Wk, Wv, Wi, Wf, Wo, Wp,
                                              Wqkvif, Wob, Wpb);
        proj_cell_f<<<dim3(B_ / 32), 256, 0, stream>>>(
            x, Wqkvif, bq, bk, bv, bi, bf, C, n, xb, C_new, n_new, ht);
        out_fused_f<<<dim3(HID_ / 128, B_ / 128), 256, 0, stream>>>(
            xb, Wob, bo, ht, Wpb, bp, h_new);
    } else {
        // fallback: round-2 path (16.6 MB workspace)
        float* ws = (float*)d_ws;
        float* q  = ws;
        float* k  = q + (size_t)B_ * D_;
        float* v  = k + (size_t)B_ * D_;
        float* ig = v + (size_t)B_ * D_;
        float* fg = ig + B_;
        ushort* ht     = (ushort*)(fg + B_);
        ushort* Wqkv_b = ht + (size_t)B_ * D_;
        ushort* Wo_b   = Wqkv_b + 196608;
        ushort* Wp_b   = Wo_b + 1048576;

        cvt_w<<<dim3(1280), 256, 0, stream>>>(Wq, Wk, Wv, Wo, Wp, Wqkv_b, Wo_b, Wp_b);
        gates_if<<<dim3(B_ / 16), 256, 0, stream>>>(x, Wi, bi, Wf, bf, ig, fg);
        proj_qkv<<<dim3(B_ / 64), 256, 0, stream>>>(x, Wqkv_b, bq, bk, bv, q, k, v);
        cell_update<<<dim3(B_), 256, 0, stream>>>(C, q, k, v, ig, fg, n, C_new, n_new, ht);
        out_fused<<<dim3(HID_ / 128, B_ / 128), 256, 0, stream>>>(
            x, Wo_b, bo, ht, Wp_b, bp, h_new);
    }
}